// Round 1
// baseline (616.948 us; speedup 1.0000x reference)
//
#include <hip/hip_runtime.h>

// Problem constants
#define B_   8
#define N_   1024
#define C_   1024
#define H_   16
#define P_   64
#define D_   64
#define MKV  1088      // P_ + N_
#define ROWS 8192      // B_*N_

typedef float f32x4 __attribute__((ext_vector_type(4)));
typedef __bf16 bf16x8 __attribute__((ext_vector_type(8)));
typedef unsigned short u16x8 __attribute__((ext_vector_type(8)));
typedef unsigned short u16x4 __attribute__((ext_vector_type(4)));

__device__ __forceinline__ unsigned short f2bf(float f) {
  unsigned u = __float_as_uint(f);
  u += 0x7fffu + ((u >> 16) & 1u);   // round-to-nearest-even
  return (unsigned short)(u >> 16);
}

#define GLDS16(g, l)                                                          \
  __builtin_amdgcn_global_load_lds(                                           \
      (const __attribute__((address_space(1))) void*)(g),                     \
      (__attribute__((address_space(3))) void*)(l), 16, 0, 0)

// ---------------------------------------------------------------------------
// fp32 -> bf16 cast (weights), 8 elems/thread
__global__ __launch_bounds__(256) void cast_bf16_k(
    const float* __restrict__ in, unsigned short* __restrict__ out, int n8) {
  int i = blockIdx.x * 256 + threadIdx.x;
  if (i >= n8) return;
  const float4 a = ((const float4*)in)[i * 2];
  const float4 c = ((const float4*)in)[i * 2 + 1];
  u16x8 o;
  o[0] = f2bf(a.x); o[1] = f2bf(a.y); o[2] = f2bf(a.z); o[3] = f2bf(a.w);
  o[4] = f2bf(c.x); o[5] = f2bf(c.y); o[6] = f2bf(c.z); o[7] = f2bf(c.w);
  *(u16x8*)(out + (size_t)i * 8) = o;
}

// ---------------------------------------------------------------------------
// LayerNorm (fp32 in) -> bf16 out.  One block per row of 1024.
__global__ __launch_bounds__(256) void ln_bf16(
    const float* __restrict__ x, const float* __restrict__ g,
    const float* __restrict__ b, unsigned short* __restrict__ out) {
  const int row = blockIdx.x, t = threadIdx.x;
  const float4 v = ((const float4*)(x + (size_t)row * 1024))[t];
  float s  = v.x + v.y + v.z + v.w;
  float s2 = v.x * v.x + v.y * v.y + v.z * v.z + v.w * v.w;
#pragma unroll
  for (int m = 1; m < 64; m <<= 1) {
    s  += __shfl_xor(s, m);
    s2 += __shfl_xor(s2, m);
  }
  __shared__ float red[8];
  if ((t & 63) == 0) { red[t >> 6] = s; red[4 + (t >> 6)] = s2; }
  __syncthreads();
  s  = red[0] + red[1] + red[2] + red[3];
  s2 = red[4] + red[5] + red[6] + red[7];
  const float mu = s * (1.0f / 1024.0f);
  const float rs = rsqrtf(s2 * (1.0f / 1024.0f) - mu * mu + 1e-5f);
  const float4 gv = ((const float4*)g)[t];
  const float4 bv = ((const float4*)b)[t];
  u16x4 o;
  o[0] = f2bf((v.x - mu) * rs * gv.x + bv.x);
  o[1] = f2bf((v.y - mu) * rs * gv.y + bv.y);
  o[2] = f2bf((v.z - mu) * rs * gv.z + bv.z);
  o[3] = f2bf((v.w - mu) * rs * gv.w + bv.w);
  *(u16x4*)(out + (size_t)row * 1024 + t * 4) = o;
}

// ---------------------------------------------------------------------------
// Prefix k/v: pk,pv [B,P,C] fp32 -> K/V buffers [B,H,MKV,D] bf16 (rows 0..P)
__global__ __launch_bounds__(256) void prefix_fill(
    const float* __restrict__ pk, const float* __restrict__ pv,
    unsigned short* __restrict__ Kb, unsigned short* __restrict__ Vb) {
  int i = blockIdx.x * 256 + threadIdx.x;  // 65536 total, 8 elems each
  int c8 = i & 127, bp = i >> 7;
  int b = bp >> 6, p = bp & 63;
  int c = c8 << 3, h = c >> 6, d = c & 63;
  size_t sidx = (size_t)bp * 1024 + c;
  size_t didx = (((size_t)(b * 16 + h)) * MKV + p) * 64 + d;
  float4 a = *(const float4*)(pk + sidx);
  float4 a2 = *(const float4*)(pk + sidx + 4);
  u16x8 o;
  o[0] = f2bf(a.x);  o[1] = f2bf(a.y);  o[2] = f2bf(a.z);  o[3] = f2bf(a.w);
  o[4] = f2bf(a2.x); o[5] = f2bf(a2.y); o[6] = f2bf(a2.z); o[7] = f2bf(a2.w);
  *(u16x8*)(Kb + didx) = o;
  a = *(const float4*)(pv + sidx);
  a2 = *(const float4*)(pv + sidx + 4);
  o[0] = f2bf(a.x);  o[1] = f2bf(a.y);  o[2] = f2bf(a.z);  o[3] = f2bf(a.w);
  o[4] = f2bf(a2.x); o[5] = f2bf(a2.y); o[6] = f2bf(a2.z); o[7] = f2bf(a2.w);
  *(u16x8*)(Vb + didx) = o;
}

// ---------------------------------------------------------------------------
// V [BH,MKV,64] -> Vt [BH,64,MKV]  (64x64 tiles through LDS, pad 66 => 4-way max)
__global__ __launch_bounds__(256) void transpose_v(
    const unsigned short* __restrict__ Vb, unsigned short* __restrict__ Vt) {
  __shared__ __align__(16) unsigned short Ts[64 * 66];
  const int kt = blockIdx.x, bh = blockIdx.y;
  const int t = threadIdx.x;
  const unsigned short* src = Vb + ((size_t)bh * MKV + kt * 64) * 64;
#pragma unroll
  for (int rnd = 0; rnd < 2; rnd++) {
    int chunk = rnd * 256 + t;
    int mr = chunk >> 3, d0 = (chunk & 7) << 3;
    u16x8 a = *(const u16x8*)(src + mr * 64 + d0);
#pragma unroll
    for (int j = 0; j < 8; j += 2)
      *(unsigned*)&Ts[mr * 66 + d0 + j] = (unsigned)a[j] | ((unsigned)a[j + 1] << 16);
  }
  __syncthreads();
#pragma unroll
  for (int rnd = 0; rnd < 2; rnd++) {
    int chunk = rnd * 256 + t;
    int dr = chunk >> 3, m0 = (chunk & 7) << 3;
    u16x8 o;
#pragma unroll
    for (int j = 0; j < 8; j++) o[j] = Ts[(m0 + j) * 66 + dr];
    *(u16x8*)(Vt + ((size_t)bh * 64 + dr) * MKV + kt * 64 + m0) = o;
  }
}

// ---------------------------------------------------------------------------
// GEMM: C[M,Nd] = A[M,K] @ Bw[Nd,K]^T, bf16 in, fp32 accum. m97 structure:
// 128x128 tile, BK=32, 4 waves each 64x64 (4x4 16x16x32 frags), global_load_lds.
// EPI 0: qkv scatter (q*0.125 -> qout, k -> kout, v -> vout)
// EPI 1: outf = resid + acc + bias   (fp32)
// EPI 2: outb = bf16(quickgelu(acc + bias))
template <int EPI>
__global__ __launch_bounds__(256) void gemm_bt(
    const unsigned short* __restrict__ A, const unsigned short* __restrict__ Bw,
    const float* __restrict__ bias, const float* __restrict__ resid,
    float* __restrict__ outf, unsigned short* __restrict__ outb,
    unsigned short* __restrict__ qout, unsigned short* __restrict__ kout,
    unsigned short* __restrict__ vout, int Ndim, int Kdim) {
  __shared__ __align__(16) unsigned short As[4096];
  __shared__ __align__(16) unsigned short Bs[4096];
  const int t = threadIdx.x;
  const int w = t >> 6, l = t & 63;
  const int wr = w >> 1, wc = w & 1;
  const int q4 = l >> 4, r15 = l & 15;
  const int bm = blockIdx.x, bn = blockIdx.y;
  const int srow = t >> 2, scol = (t & 3) << 3;
  const unsigned short* Ap = A + (size_t)(bm * 128 + srow) * Kdim + scol;
  const unsigned short* Bp = Bw + (size_t)(bn * 128 + srow) * Kdim + scol;
  f32x4 acc[4][4] = {};
  const int ard = (wr * 64 + r15) * 32 + q4 * 8;
  const int brd = (wc * 64 + r15) * 32 + q4 * 8;
  for (int kt = 0; kt < Kdim; kt += 32) {
    GLDS16(Ap, &As[t * 8]);
    GLDS16(Ap + (size_t)64 * Kdim, &As[2048 + t * 8]);
    GLDS16(Bp, &Bs[t * 8]);
    GLDS16(Bp + (size_t)64 * Kdim, &Bs[2048 + t * 8]);
    Ap += 32; Bp += 32;
    __syncthreads();   // drains vmcnt+lgkmcnt before barrier (m97 pattern)
    bf16x8 af[4], bfv[4];
#pragma unroll
    for (int mi = 0; mi < 4; mi++) af[mi] = *(const bf16x8*)&As[ard + mi * 512];
#pragma unroll
    for (int ni = 0; ni < 4; ni++) bfv[ni] = *(const bf16x8*)&Bs[brd + ni * 512];
#pragma unroll
    for (int mi = 0; mi < 4; mi++)
#pragma unroll
      for (int ni = 0; ni < 4; ni++)
        acc[mi][ni] = __builtin_amdgcn_mfma_f32_16x16x32_bf16(
            af[mi], bfv[ni], acc[mi][ni], 0, 0, 0);
    __syncthreads();
  }
  // Epilogue.  D layout: row=(l>>4)*4+reg, col=l&15 (m89/m91 verified).
  const int orow0 = bm * 128 + wr * 64 + q4 * 4;
  const int ocol0 = bn * 128 + wc * 64 + r15;
  if (EPI == 0) {
    const int which = (bn * 128) >> 10;  // uniform per block (128 | 1024)
#pragma unroll
    for (int mi = 0; mi < 4; mi++)
#pragma unroll
      for (int ni = 0; ni < 4; ni++)
#pragma unroll
        for (int r = 0; r < 4; r++) {
          int m = orow0 + mi * 16 + r;
          int c = ocol0 + ni * 16;
          int cc = c & 1023;
          int h = cc >> 6, d = cc & 63;
          int b = m >> 10, n = m & 1023;
          float v = acc[mi][ni][r];
          if (which == 0)
            qout[(((size_t)(b * 16 + h)) * 1024 + n) * 64 + d] = f2bf(v * 0.125f);
          else if (which == 1)
            kout[(((size_t)(b * 16 + h)) * MKV + 64 + n) * 64 + d] = f2bf(v);
          else
            vout[(((size_t)(b * 16 + h)) * MKV + 64 + n) * 64 + d] = f2bf(v);
        }
  } else if (EPI == 1) {
#pragma unroll
    for (int mi = 0; mi < 4; mi++)
#pragma unroll
      for (int ni = 0; ni < 4; ni++)
#pragma unroll
        for (int r = 0; r < 4; r++) {
          int c = ocol0 + ni * 16;
          size_t idx = (size_t)(orow0 + mi * 16 + r) * Ndim + c;
          outf[idx] = resid[idx] + acc[mi][ni][r] + bias[c];
        }
  } else {
#pragma unroll
    for (int mi = 0; mi < 4; mi++)
#pragma unroll
      for (int ni = 0; ni < 4; ni++)
#pragma unroll
        for (int r = 0; r < 4; r++) {
          int c = ocol0 + ni * 16;
          size_t idx = (size_t)(orow0 + mi * 16 + r) * Ndim + c;
          float z = acc[mi][ni][r] + bias[c];
          outb[idx] = f2bf(z / (1.f + __expf(-1.702f * z)));
        }
  }
}

// ---------------------------------------------------------------------------
// Flash attention. Block = 4 waves, 64 q-rows (wave w owns 16). 17 KV tiles of 64.
// K and V(transposed) fragments read directly from global (L1/L2-resident).
// P goes through per-wave XOR-swizzled LDS (D-layout -> A-frag layout).
__global__ __launch_bounds__(256) void flash_attn(
    const unsigned short* __restrict__ Qb, const unsigned short* __restrict__ Kb,
    const unsigned short* __restrict__ Vt, unsigned short* __restrict__ Ob) {
  __shared__ __align__(16) unsigned short P_lds[4][1024];  // [wave][16 rows][64 cols]
  const int t = threadIdx.x;
  const int w = t >> 6, l = t & 63;
  const int q4 = l >> 4, r15 = l & 15;
  const int qt = blockIdx.x, bh = blockIdx.y;
  const unsigned short* Qrow = Qb + ((size_t)bh * 1024 + qt * 64 + w * 16 + r15) * 64;
  const bf16x8 qf0 = *(const bf16x8*)(Qrow + q4 * 8);
  const bf16x8 qf1 = *(const bf16x8*)(Qrow + 32 + q4 * 8);
  const unsigned short* Kbh = Kb + (size_t)bh * MKV * 64;
  const unsigned short* Vbh = Vt + (size_t)bh * 64 * MKV;
  f32x4 Oa[4] = {};
  float mrow[4] = {-1e30f, -1e30f, -1e30f, -1e30f};
  float lrow[4] = {0.f, 0.f, 0.f, 0.f};
  char* Pbase = (char*)&P_lds[w][0];
  for (int kt = 0; kt < 17; ++kt) {
    f32x4 S[4];
#pragma unroll
    for (int jc = 0; jc < 4; jc++) {
      const unsigned short* Krow = Kbh + (size_t)(kt * 64 + jc * 16 + r15) * 64 + q4 * 8;
      bf16x8 k0 = *(const bf16x8*)Krow;
      bf16x8 k1 = *(const bf16x8*)(Krow + 32);
      f32x4 a = {};
      a = __builtin_amdgcn_mfma_f32_16x16x32_bf16(qf0, k0, a, 0, 0, 0);
      a = __builtin_amdgcn_mfma_f32_16x16x32_bf16(qf1, k1, a, 0, 0, 0);
      S[jc] = a;
    }
#pragma unroll
    for (int r = 0; r < 4; r++) {
      float mt = fmaxf(fmaxf(S[0][r], S[1][r]), fmaxf(S[2][r], S[3][r]));
      mt = fmaxf(mt, __shfl_xor(mt, 1));
      mt = fmaxf(mt, __shfl_xor(mt, 2));
      mt = fmaxf(mt, __shfl_xor(mt, 4));
      mt = fmaxf(mt, __shfl_xor(mt, 8));
      float mn = fmaxf(mrow[r], mt);
      float scl = __expf(mrow[r] - mn);
      mrow[r] = mn;
      float rs = 0.f;
#pragma unroll
      for (int jc = 0; jc < 4; jc++) {
        float p = __expf(S[jc][r] - mn);
        S[jc][r] = p;
        rs += p;
      }
      rs += __shfl_xor(rs, 1);
      rs += __shfl_xor(rs, 2);
      rs += __shfl_xor(rs, 4);
      rs += __shfl_xor(rs, 8);
      lrow[r] = lrow[r] * scl + rs;
#pragma unroll
      for (int db = 0; db < 4; db++) Oa[db][r] *= scl;
      const int prow = q4 * 4 + r;
      const int rswz = (prow & 7) << 4;
#pragma unroll
      for (int jc = 0; jc < 4; jc++) {
        float p0 = S[jc][r];
        float p1 = __shfl_xor(p0, 1);
        if (!(l & 1)) {
          unsigned pk2 = (unsigned)f2bf(p0) | ((unsigned)f2bf(p1) << 16);
          int col2 = (jc * 16 + r15) * 2;
          *(unsigned*)(Pbase + prow * 128 + (col2 ^ rswz)) = pk2;
        }
      }
    }
    // PV: A = P (rows l&15), B = V^T rows (cols l&15). Same wave wrote P -> in-order LDS.
#pragma unroll
    for (int kk = 0; kk < 2; kk++) {
      bf16x8 pa = *(const bf16x8*)(Pbase + r15 * 128 +
                                   ((kk * 64 + q4 * 16) ^ ((r15 & 7) << 4)));
#pragma unroll
      for (int db = 0; db < 4; db++) {
        const unsigned short* Vrow =
            Vbh + (size_t)(db * 16 + r15) * MKV + kt * 64 + kk * 32 + q4 * 8;
        bf16x8 vb = *(const bf16x8*)Vrow;
        Oa[db] = __builtin_amdgcn_mfma_f32_16x16x32_bf16(pa, vb, Oa[db], 0, 0, 0);
      }
    }
  }
  const int b = bh >> 4, h = bh & 15;
  float inv[4];
#pragma unroll
  for (int r = 0; r < 4; r++) inv[r] = 1.f / lrow[r];
#pragma unroll
  for (int db = 0; db < 4; db++)
#pragma unroll
    for (int r = 0; r < 4; r++) {
      int n = qt * 64 + w * 16 + q4 * 4 + r;
      Ob[((size_t)b * 1024 + n) * 1024 + h * 64 + db * 16 + r15] =
          f2bf(Oa[db][r] * inv[r]);
    }
}

// ---------------------------------------------------------------------------
extern "C" void kernel_launch(void* const* d_in, const int* in_sizes, int n_in,
                              void* d_out, int out_size, void* d_ws, size_t ws_size,
                              hipStream_t stream) {
  const float* x       = (const float*)d_in[0];
  const float* pk      = (const float*)d_in[1];
  const float* pv      = (const float*)d_in[2];
  const float* qkv_w   = (const float*)d_in[3];
  const float* proj_w  = (const float*)d_in[4];
  const float* proj_b  = (const float*)d_in[5];
  const float* ln1_g   = (const float*)d_in[6];
  const float* ln1_b   = (const float*)d_in[7];
  const float* ln2_g   = (const float*)d_in[8];
  const float* ln2_b   = (const float*)d_in[9];
  const float* fc_w    = (const float*)d_in[10];
  const float* fc_b    = (const float*)d_in[11];
  const float* cproj_w = (const float*)d_in[12];
  const float* cproj_b = (const float*)d_in[13];
  float* out = (float*)d_out;
  char* ws = (char*)d_ws;

  // Workspace layout (aliased; see per-stage liveness):
  unsigned short* qkv_wb   = (unsigned short*)(ws + 0);          // 6291456
  unsigned short* proj_wb  = (unsigned short*)(ws + 6291456);    // 2097152
  unsigned short* fc_wb    = (unsigned short*)(ws + 8388608);    // 8388608
  unsigned short* cproj_wb = (unsigned short*)(ws + 16777216);   // 8388608
  float*          x1       = (float*)(ws + 25165824);            // 33554432
  unsigned short* h1       = (unsigned short*)(ws + 58720256);   // 16777216
  unsigned short* o_b      = h1;                                 // alias (h1 dead)
  unsigned short* h2       = (unsigned short*)(ws + 75497472);   // 16777216
  unsigned short* q_buf    = (unsigned short*)(ws + 92274688);   // 16777216
  unsigned short* Kb       = (unsigned short*)(ws + 109051904);  // 17825792
  unsigned short* Vb       = (unsigned short*)(ws + 126877696);  // 17825792
  unsigned short* Vt       = (unsigned short*)(ws + 144703488);  // 17825792
  unsigned short* h3       = (unsigned short*)(ws + 92274688);   // alias q/K/V/Vt (dead)
  if (ws_size < 162529280u) return;  // fail loudly (output stays poisoned)

  cast_bf16_k<<<1536, 256, 0, stream>>>(qkv_w, qkv_wb, 393216);
  cast_bf16_k<<<512, 256, 0, stream>>>(proj_w, proj_wb, 131072);
  cast_bf16_k<<<2048, 256, 0, stream>>>(fc_w, fc_wb, 524288);
  cast_bf16_k<<<2048, 256, 0, stream>>>(cproj_w, cproj_wb, 524288);
  ln_bf16<<<ROWS, 256, 0, stream>>>(x, ln1_g, ln1_b, h1);
  prefix_fill<<<256, 256, 0, stream>>>(pk, pv, Kb, Vb);
  gemm_bt<0><<<dim3(64, 24), 256, 0, stream>>>(h1, qkv_wb, nullptr, nullptr, nullptr,
                                               nullptr, q_buf, Kb, Vb, 3072, 1024);
  transpose_v<<<dim3(17, 128), 256, 0, stream>>>(Vb, Vt);
  flash_attn<<<dim3(16, 128), 256, 0, stream>>>(q_buf, Kb, Vt, o_b);
  gemm_bt<1><<<dim3(64, 8), 256, 0, stream>>>(o_b, proj_wb, proj_b, x, x1, nullptr,
                                              nullptr, nullptr, nullptr, 1024, 1024);
  ln_bf16<<<ROWS, 256, 0, stream>>>(x1, ln2_g, ln2_b, h2);
  gemm_bt<2><<<dim3(64, 32), 256, 0, stream>>>(h2, fc_wb, fc_b, nullptr, nullptr, h3,
                                               nullptr, nullptr, nullptr, 4096, 1024);
  gemm_bt<1><<<dim3(64, 8), 256, 0, stream>>>(h3, cproj_wb, cproj_b, x1, out, nullptr,
                                              nullptr, nullptr, nullptr, 1024, 4096);
}

// Round 2
// 609.567 us; speedup vs baseline: 1.0121x; 1.0121x over previous
//
#include <hip/hip_runtime.h>

// Problem constants
#define B_   8
#define N_   1024
#define C_   1024
#define H_   16
#define P_   64
#define D_   64
#define MKV  1088      // P_ + N_
#define ROWS 8192      // B_*N_

typedef float f32x4 __attribute__((ext_vector_type(4)));
typedef __bf16 bf16x8 __attribute__((ext_vector_type(8)));
typedef unsigned short u16x8 __attribute__((ext_vector_type(8)));
typedef unsigned short u16x4 __attribute__((ext_vector_type(4)));

__device__ __forceinline__ unsigned short f2bf(float f) {
  unsigned u = __float_as_uint(f);
  u += 0x7fffu + ((u >> 16) & 1u);   // round-to-nearest-even
  return (unsigned short)(u >> 16);
}

#define GLDS16(g, l)                                                          \
  __builtin_amdgcn_global_load_lds(                                           \
      (const __attribute__((address_space(1))) void*)(g),                     \
      (__attribute__((address_space(3))) void*)(l), 16, 0, 0)

// ---------------------------------------------------------------------------
// fp32 -> bf16 cast (weights), 8 elems/thread
__global__ __launch_bounds__(256) void cast_bf16_k(
    const float* __restrict__ in, unsigned short* __restrict__ out, int n8) {
  int i = blockIdx.x * 256 + threadIdx.x;
  if (i >= n8) return;
  const float4 a = ((const float4*)in)[i * 2];
  const float4 c = ((const float4*)in)[i * 2 + 1];
  u16x8 o;
  o[0] = f2bf(a.x); o[1] = f2bf(a.y); o[2] = f2bf(a.z); o[3] = f2bf(a.w);
  o[4] = f2bf(c.x); o[5] = f2bf(c.y); o[6] = f2bf(c.z); o[7] = f2bf(c.w);
  *(u16x8*)(out + (size_t)i * 8) = o;
}

// ---------------------------------------------------------------------------
// LayerNorm (fp32 in) -> bf16 out.  One block per row of 1024.
__global__ __launch_bounds__(256) void ln_bf16(
    const float* __restrict__ x, const float* __restrict__ g,
    const float* __restrict__ b, unsigned short* __restrict__ out) {
  const int row = blockIdx.x, t = threadIdx.x;
  const float4 v = ((const float4*)(x + (size_t)row * 1024))[t];
  float s  = v.x + v.y + v.z + v.w;
  float s2 = v.x * v.x + v.y * v.y + v.z * v.z + v.w * v.w;
#pragma unroll
  for (int m = 1; m < 64; m <<= 1) {
    s  += __shfl_xor(s, m);
    s2 += __shfl_xor(s2, m);
  }
  __shared__ float red[8];
  if ((t & 63) == 0) { red[t >> 6] = s; red[4 + (t >> 6)] = s2; }
  __syncthreads();
  s  = red[0] + red[1] + red[2] + red[3];
  s2 = red[4] + red[5] + red[6] + red[7];
  const float mu = s * (1.0f / 1024.0f);
  const float rs = rsqrtf(s2 * (1.0f / 1024.0f) - mu * mu + 1e-5f);
  const float4 gv = ((const float4*)g)[t];
  const float4 bv = ((const float4*)b)[t];
  u16x4 o;
  o[0] = f2bf((v.x - mu) * rs * gv.x + bv.x);
  o[1] = f2bf((v.y - mu) * rs * gv.y + bv.y);
  o[2] = f2bf((v.z - mu) * rs * gv.z + bv.z);
  o[3] = f2bf((v.w - mu) * rs * gv.w + bv.w);
  *(u16x4*)(out + (size_t)row * 1024 + t * 4) = o;
}

// ---------------------------------------------------------------------------
// Prefix k/v: pk,pv [B,P,C] fp32 -> K/V buffers [B,H,MKV,D] bf16 (rows 0..P)
__global__ __launch_bounds__(256) void prefix_fill(
    const float* __restrict__ pk, const float* __restrict__ pv,
    unsigned short* __restrict__ Kb, unsigned short* __restrict__ Vb) {
  int i = blockIdx.x * 256 + threadIdx.x;  // 65536 total, 8 elems each
  int c8 = i & 127, bp = i >> 7;
  int b = bp >> 6, p = bp & 63;
  int c = c8 << 3, h = c >> 6, d = c & 63;
  size_t sidx = (size_t)bp * 1024 + c;
  size_t didx = (((size_t)(b * 16 + h)) * MKV + p) * 64 + d;
  float4 a = *(const float4*)(pk + sidx);
  float4 a2 = *(const float4*)(pk + sidx + 4);
  u16x8 o;
  o[0] = f2bf(a.x);  o[1] = f2bf(a.y);  o[2] = f2bf(a.z);  o[3] = f2bf(a.w);
  o[4] = f2bf(a2.x); o[5] = f2bf(a2.y); o[6] = f2bf(a2.z); o[7] = f2bf(a2.w);
  *(u16x8*)(Kb + didx) = o;
  a = *(const float4*)(pv + sidx);
  a2 = *(const float4*)(pv + sidx + 4);
  o[0] = f2bf(a.x);  o[1] = f2bf(a.y);  o[2] = f2bf(a.z);  o[3] = f2bf(a.w);
  o[4] = f2bf(a2.x); o[5] = f2bf(a2.y); o[6] = f2bf(a2.z); o[7] = f2bf(a2.w);
  *(u16x8*)(Vb + didx) = o;
}

// ---------------------------------------------------------------------------
// V [BH,MKV,64] -> Vt [BH,64,MKV]  (64x64 tiles through LDS, pad 66 => 4-way max)
__global__ __launch_bounds__(256) void transpose_v(
    const unsigned short* __restrict__ Vb, unsigned short* __restrict__ Vt) {
  __shared__ __align__(16) unsigned short Ts[64 * 66];
  const int kt = blockIdx.x, bh = blockIdx.y;
  const int t = threadIdx.x;
  const unsigned short* src = Vb + ((size_t)bh * MKV + kt * 64) * 64;
#pragma unroll
  for (int rnd = 0; rnd < 2; rnd++) {
    int chunk = rnd * 256 + t;
    int mr = chunk >> 3, d0 = (chunk & 7) << 3;
    u16x8 a = *(const u16x8*)(src + mr * 64 + d0);
#pragma unroll
    for (int j = 0; j < 8; j += 2)
      *(unsigned*)&Ts[mr * 66 + d0 + j] = (unsigned)a[j] | ((unsigned)a[j + 1] << 16);
  }
  __syncthreads();
#pragma unroll
  for (int rnd = 0; rnd < 2; rnd++) {
    int chunk = rnd * 256 + t;
    int dr = chunk >> 3, m0 = (chunk & 7) << 3;
    u16x8 o;
#pragma unroll
    for (int j = 0; j < 8; j++) o[j] = Ts[(m0 + j) * 66 + dr];
    *(u16x8*)(Vt + ((size_t)bh * 64 + dr) * MKV + kt * 64 + m0) = o;
  }
}

// ---------------------------------------------------------------------------
// GEMM: C[M,Nd] = A[M,K] @ Bw[Nd,K]^T, bf16 in, fp32 accum. m97 structure:
// 128x128 tile, BK=32, 4 waves each 64x64 (4x4 16x16x32 frags), global_load_lds.
// EPI 0: qkv scatter (q*0.125 -> qout, k -> kout, v -> vout)
// EPI 1: outf = resid + acc + bias   (fp32)
// EPI 2: outb = bf16(quickgelu(acc + bias))
template <int EPI>
__global__ __launch_bounds__(256) void gemm_bt(
    const unsigned short* __restrict__ A, const unsigned short* __restrict__ Bw,
    const float* __restrict__ bias, const float* __restrict__ resid,
    float* __restrict__ outf, unsigned short* __restrict__ outb,
    unsigned short* __restrict__ qout, unsigned short* __restrict__ kout,
    unsigned short* __restrict__ vout, int Ndim, int Kdim) {
  __shared__ __align__(16) unsigned short As[4096];
  __shared__ __align__(16) unsigned short Bs[4096];
  const int t = threadIdx.x;
  const int w = t >> 6, l = t & 63;
  const int wr = w >> 1, wc = w & 1;
  const int q4 = l >> 4, r15 = l & 15;
  const int bm = blockIdx.x, bn = blockIdx.y;
  const int srow = t >> 2, scol = (t & 3) << 3;
  const unsigned short* Ap = A + (size_t)(bm * 128 + srow) * Kdim + scol;
  const unsigned short* Bp = Bw + (size_t)(bn * 128 + srow) * Kdim + scol;
  f32x4 acc[4][4] = {};
  const int ard = (wr * 64 + r15) * 32 + q4 * 8;
  const int brd = (wc * 64 + r15) * 32 + q4 * 8;
  for (int kt = 0; kt < Kdim; kt += 32) {
    GLDS16(Ap, &As[t * 8]);
    GLDS16(Ap + (size_t)64 * Kdim, &As[2048 + t * 8]);
    GLDS16(Bp, &Bs[t * 8]);
    GLDS16(Bp + (size_t)64 * Kdim, &Bs[2048 + t * 8]);
    Ap += 32; Bp += 32;
    __syncthreads();   // drains vmcnt+lgkmcnt before barrier (m97 pattern)
    bf16x8 af[4], bfv[4];
#pragma unroll
    for (int mi = 0; mi < 4; mi++) af[mi] = *(const bf16x8*)&As[ard + mi * 512];
#pragma unroll
    for (int ni = 0; ni < 4; ni++) bfv[ni] = *(const bf16x8*)&Bs[brd + ni * 512];
#pragma unroll
    for (int mi = 0; mi < 4; mi++)
#pragma unroll
      for (int ni = 0; ni < 4; ni++)
        acc[mi][ni] = __builtin_amdgcn_mfma_f32_16x16x32_bf16(
            af[mi], bfv[ni], acc[mi][ni], 0, 0, 0);
    __syncthreads();
  }
  // Epilogue.  D layout: row=(l>>4)*4+reg, col=l&15 (m89/m91 verified).
  const int orow0 = bm * 128 + wr * 64 + q4 * 4;
  const int ocol0 = bn * 128 + wc * 64 + r15;
  if (EPI == 0) {
    const int which = (bn * 128) >> 10;  // uniform per block (128 | 1024)
#pragma unroll
    for (int mi = 0; mi < 4; mi++)
#pragma unroll
      for (int ni = 0; ni < 4; ni++)
#pragma unroll
        for (int r = 0; r < 4; r++) {
          int m = orow0 + mi * 16 + r;
          int c = ocol0 + ni * 16;
          int cc = c & 1023;
          int h = cc >> 6, d = cc & 63;
          int b = m >> 10, n = m & 1023;
          float v = acc[mi][ni][r];
          if (which == 0)
            qout[(((size_t)(b * 16 + h)) * 1024 + n) * 64 + d] = f2bf(v * 0.125f);
          else if (which == 1)
            kout[(((size_t)(b * 16 + h)) * MKV + 64 + n) * 64 + d] = f2bf(v);
          else
            vout[(((size_t)(b * 16 + h)) * MKV + 64 + n) * 64 + d] = f2bf(v);
        }
  } else if (EPI == 1) {
#pragma unroll
    for (int mi = 0; mi < 4; mi++)
#pragma unroll
      for (int ni = 0; ni < 4; ni++)
#pragma unroll
        for (int r = 0; r < 4; r++) {
          int c = ocol0 + ni * 16;
          size_t idx = (size_t)(orow0 + mi * 16 + r) * Ndim + c;
          outf[idx] = resid[idx] + acc[mi][ni][r] + bias[c];
        }
  } else {
#pragma unroll
    for (int mi = 0; mi < 4; mi++)
#pragma unroll
      for (int ni = 0; ni < 4; ni++)
#pragma unroll
        for (int r = 0; r < 4; r++) {
          int c = ocol0 + ni * 16;
          size_t idx = (size_t)(orow0 + mi * 16 + r) * Ndim + c;
          float z = acc[mi][ni][r] + bias[c];
          outb[idx] = f2bf(z / (1.f + __expf(-1.702f * z)));
        }
  }
}

// ---------------------------------------------------------------------------
// Flash attention v2 — swapped QK^T (S^T = K·Q^T) so each lane owns the full
// P-slice of one q-row; softmax is 2 shuffles; P never leaves registers.
// grid = (bh, qt) so a bh's 16 q-tiles land on one XCD (id % 8 == bh % 8).
// Per wave: 16 q-rows. 17 KV tiles of 64. K read from Kb, V^T from Vt (global,
// L1/L2-resident).
__global__ __launch_bounds__(256) void flash_attn(
    const unsigned short* __restrict__ Qb, const unsigned short* __restrict__ Kb,
    const unsigned short* __restrict__ Vt, unsigned short* __restrict__ Ob) {
  const int t = threadIdx.x;
  const int w = t >> 6, l = t & 63;
  const int g = l >> 4, r15 = l & 15;
  const int bh = blockIdx.x, qt = blockIdx.y;
  // Q fragment (B-operand): lane holds Q[q = r15-row][d = g*8+j]
  const unsigned short* Qrow = Qb + ((size_t)bh * 1024 + qt * 64 + w * 16 + r15) * 64;
  const bf16x8 qf0 = *(const bf16x8*)(Qrow + g * 8);
  const bf16x8 qf1 = *(const bf16x8*)(Qrow + 32 + g * 8);
  const unsigned short* Kbh = Kb + (size_t)bh * MKV * 64;
  const unsigned short* Vbh = Vt + (size_t)bh * 64 * MKV;
  f32x4 Oa[4] = {};            // Oa[db][r] = O[q=r15][d=db*16+4g+r]  (O^T acc)
  float m = -1e30f, lsum = 0.f;
  const int src0 = r15 + ((l & 16) << 1);  // r15 + 32*(g&1)
  const bool loHalf = (l < 32);            // g<2 -> lower 16 k of the 32-block
  for (int kt = 0; kt < 17; ++kt) {
    const unsigned short* Kt0 = Kbh + (size_t)(kt * 64 + r15) * 64 + g * 8;
    f32x4 S[4];  // S[jc][r] = S^T[k = jc*16+4g+r][q = r15]
#pragma unroll
    for (int jc = 0; jc < 4; jc++) {
      const unsigned short* Krow = Kt0 + jc * 1024;
      bf16x8 k0 = *(const bf16x8*)Krow;
      bf16x8 k1 = *(const bf16x8*)(Krow + 32);
      f32x4 a = {};
      a = __builtin_amdgcn_mfma_f32_16x16x32_bf16(k0, qf0, a, 0, 0, 0);
      a = __builtin_amdgcn_mfma_f32_16x16x32_bf16(k1, qf1, a, 0, 0, 0);
      S[jc] = a;
    }
    // ---- online softmax: each lane owns q=r15; 16 local vals + 2 shuffles
    float mx = S[0][0];
#pragma unroll
    for (int jc = 0; jc < 4; jc++)
#pragma unroll
      for (int r = 0; r < 4; r++) mx = fmaxf(mx, S[jc][r]);
    mx = fmaxf(mx, __shfl_xor(mx, 16));
    mx = fmaxf(mx, __shfl_xor(mx, 32));
    const float mn = fmaxf(m, mx);
    const float scl = __expf(m - mn);
    m = mn;
    float rs = 0.f;
#pragma unroll
    for (int jc = 0; jc < 4; jc++)
#pragma unroll
      for (int r = 0; r < 4; r++) {
        float p = __expf(S[jc][r] - mn);
        S[jc][r] = p;
        rs += p;
      }
    rs += __shfl_xor(rs, 16);
    rs += __shfl_xor(rs, 32);
    lsum = lsum * scl + rs;
#pragma unroll
    for (int db = 0; db < 4; db++)
#pragma unroll
      for (int r = 0; r < 4; r++) Oa[db][r] *= scl;
    // ---- pack P to bf16 words: pw[jc][0]=p0|p1, pw[jc][1]=p2|p3
    unsigned pw[4][2];
#pragma unroll
    for (int jc = 0; jc < 4; jc++) {
      pw[jc][0] = (unsigned)f2bf(S[jc][0]) | ((unsigned)f2bf(S[jc][1]) << 16);
      pw[jc][1] = (unsigned)f2bf(S[jc][2]) | ((unsigned)f2bf(S[jc][3]) << 16);
    }
    // ---- PV: rebuild B-frag (P^T[k][q], k=8g+j) via lane exchange, then
    // O^T += mfma(V^T_frag, P_frag)
#pragma unroll
    for (int kk = 0; kk < 2; kk++) {
      const unsigned a0 = pw[2 * kk][0], a1 = pw[2 * kk][1];
      const unsigned b0 = pw[2 * kk + 1][0], b1 = pw[2 * kk + 1][1];
      unsigned wA0 = (unsigned)__shfl((int)a0, src0);
      unsigned wA1 = (unsigned)__shfl((int)a1, src0);
      unsigned wB0 = (unsigned)__shfl((int)b0, src0);
      unsigned wB1 = (unsigned)__shfl((int)b1, src0);
      unsigned wA0h = (unsigned)__shfl((int)a0, src0 + 16);
      unsigned wA1h = (unsigned)__shfl((int)a1, src0 + 16);
      unsigned wB0h = (unsigned)__shfl((int)b0, src0 + 16);
      unsigned wB1h = (unsigned)__shfl((int)b1, src0 + 16);
      union { unsigned u[4]; bf16x8 v; } pf;
      pf.u[0] = loHalf ? wA0 : wB0;
      pf.u[1] = loHalf ? wA1 : wB1;
      pf.u[2] = loHalf ? wA0h : wB0h;
      pf.u[3] = loHalf ? wA1h : wB1h;
#pragma unroll
      for (int db = 0; db < 4; db++) {
        const unsigned short* Vrow =
            Vbh + (size_t)(db * 16 + r15) * MKV + kt * 64 + kk * 32 + g * 8;
        bf16x8 va = *(const bf16x8*)Vrow;
        Oa[db] = __builtin_amdgcn_mfma_f32_16x16x32_bf16(va, pf.v, Oa[db], 0, 0, 0);
      }
    }
  }
  const int b = bh >> 4, h = bh & 15;
  const float inv = 1.f / lsum;
  const int n = qt * 64 + w * 16 + r15;
#pragma unroll
  for (int db = 0; db < 4; db++) {
    u16x4 o;
#pragma unroll
    for (int r = 0; r < 4; r++) o[r] = f2bf(Oa[db][r] * inv);
    *(u16x4*)(Ob + ((size_t)b * 1024 + n) * 1024 + h * 64 + db * 16 + g * 4) = o;
  }
}

// ---------------------------------------------------------------------------
extern "C" void kernel_launch(void* const* d_in, const int* in_sizes, int n_in,
                              void* d_out, int out_size, void* d_ws, size_t ws_size,
                              hipStream_t stream) {
  const float* x       = (const float*)d_in[0];
  const float* pk      = (const float*)d_in[1];
  const float* pv      = (const float*)d_in[2];
  const float* qkv_w   = (const float*)d_in[3];
  const float* proj_w  = (const float*)d_in[4];
  const float* proj_b  = (const float*)d_in[5];
  const float* ln1_g   = (const float*)d_in[6];
  const float* ln1_b   = (const float*)d_in[7];
  const float* ln2_g   = (const float*)d_in[8];
  const float* ln2_b   = (const float*)d_in[9];
  const float* fc_w    = (const float*)d_in[10];
  const float* fc_b    = (const float*)d_in[11];
  const float* cproj_w = (const float*)d_in[12];
  const float* cproj_b = (const float*)d_in[13];
  float* out = (float*)d_out;
  char* ws = (char*)d_ws;

  // Workspace layout (aliased; see per-stage liveness):
  unsigned short* qkv_wb   = (unsigned short*)(ws + 0);          // 6291456
  unsigned short* proj_wb  = (unsigned short*)(ws + 6291456);    // 2097152
  unsigned short* fc_wb    = (unsigned short*)(ws + 8388608);    // 8388608
  unsigned short* cproj_wb = (unsigned short*)(ws + 16777216);   // 8388608
  float*          x1       = (float*)(ws + 25165824);            // 33554432
  unsigned short* h1       = (unsigned short*)(ws + 58720256);   // 16777216
  unsigned short* o_b      = h1;                                 // alias (h1 dead)
  unsigned short* h2       = (unsigned short*)(ws + 75497472);   // 16777216
  unsigned short* q_buf    = (unsigned short*)(ws + 92274688);   // 16777216
  unsigned short* Kb       = (unsigned short*)(ws + 109051904);  // 17825792
  unsigned short* Vb       = (unsigned short*)(ws + 126877696);  // 17825792
  unsigned short* Vt       = (unsigned short*)(ws + 144703488);  // 17825792
  unsigned short* h3       = (unsigned short*)(ws + 92274688);   // alias q/K/V/Vt (dead)
  if (ws_size < 162529280u) return;  // fail loudly (output stays poisoned)

  cast_bf16_k<<<1536, 256, 0, stream>>>(qkv_w, qkv_wb, 393216);
  cast_bf16_k<<<512, 256, 0, stream>>>(proj_w, proj_wb, 131072);
  cast_bf16_k<<<2048, 256, 0, stream>>>(fc_w, fc_wb, 524288);
  cast_bf16_k<<<2048, 256, 0, stream>>>(cproj_w, cproj_wb, 524288);
  ln_bf16<<<ROWS, 256, 0, stream>>>(x, ln1_g, ln1_b, h1);
  prefix_fill<<<256, 256, 0, stream>>>(pk, pv, Kb, Vb);
  gemm_bt<0><<<dim3(64, 24), 256, 0, stream>>>(h1, qkv_wb, nullptr, nullptr, nullptr,
                                               nullptr, q_buf, Kb, Vb, 3072, 1024);
  transpose_v<<<dim3(17, 128), 256, 0, stream>>>(Vb, Vt);
  flash_attn<<<dim3(128, 16), 256, 0, stream>>>(q_buf, Kb, Vt, o_b);
  gemm_bt<1><<<dim3(64, 8), 256, 0, stream>>>(o_b, proj_wb, proj_b, x, x1, nullptr,
                                              nullptr, nullptr, nullptr, 1024, 1024);
  ln_bf16<<<ROWS, 256, 0, stream>>>(x1, ln2_g, ln2_b, h2);
  gemm_bt<2><<<dim3(64, 32), 256, 0, stream>>>(h2, fc_wb, fc_b, nullptr, nullptr, h3,
                                               nullptr, nullptr, nullptr, 4096, 1024);
  gemm_bt<1><<<dim3(64, 8), 256, 0, stream>>>(h3, cproj_wb, cproj_b, x1, out, nullptr,
                                              nullptr, nullptr, nullptr, 1024, 4096);
}

// Round 3
// 442.613 us; speedup vs baseline: 1.3939x; 1.3772x over previous
//
#include <hip/hip_runtime.h>

// Problem constants
#define B_   8
#define N_   1024
#define C_   1024
#define H_   16
#define P_   64
#define D_   64
#define MKV  1088      // P_ + N_
#define ROWS 8192      // B_*N_

typedef float f32x4 __attribute__((ext_vector_type(4)));
typedef __bf16 bf16x8 __attribute__((ext_vector_type(8)));
typedef unsigned short u16x8 __attribute__((ext_vector_type(8)));
typedef unsigned short u16x4 __attribute__((ext_vector_type(4)));

__device__ __forceinline__ unsigned short f2bf(float f) {
  unsigned u = __float_as_uint(f);
  u += 0x7fffu + ((u >> 16) & 1u);   // round-to-nearest-even
  return (unsigned short)(u >> 16);
}

#define GLDS16(g, l)                                                          \
  __builtin_amdgcn_global_load_lds(                                           \
      (const __attribute__((address_space(1))) void*)(g),                     \
      (__attribute__((address_space(3))) void*)(l), 16, 0, 0)

// ---------------------------------------------------------------------------
// fp32 -> bf16 cast (weights), 8 elems/thread
__global__ __launch_bounds__(256) void cast_bf16_k(
    const float* __restrict__ in, unsigned short* __restrict__ out, int n8) {
  int i = blockIdx.x * 256 + threadIdx.x;
  if (i >= n8) return;
  const float4 a = ((const float4*)in)[i * 2];
  const float4 c = ((const float4*)in)[i * 2 + 1];
  u16x8 o;
  o[0] = f2bf(a.x); o[1] = f2bf(a.y); o[2] = f2bf(a.z); o[3] = f2bf(a.w);
  o[4] = f2bf(c.x); o[5] = f2bf(c.y); o[6] = f2bf(c.z); o[7] = f2bf(c.w);
  *(u16x8*)(out + (size_t)i * 8) = o;
}

// ---------------------------------------------------------------------------
// LayerNorm (fp32 in) -> bf16 out.  One block per row of 1024.
__global__ __launch_bounds__(256) void ln_bf16(
    const float* __restrict__ x, const float* __restrict__ g,
    const float* __restrict__ b, unsigned short* __restrict__ out) {
  const int row = blockIdx.x, t = threadIdx.x;
  const float4 v = ((const float4*)(x + (size_t)row * 1024))[t];
  float s  = v.x + v.y + v.z + v.w;
  float s2 = v.x * v.x + v.y * v.y + v.z * v.z + v.w * v.w;
#pragma unroll
  for (int m = 1; m < 64; m <<= 1) {
    s  += __shfl_xor(s, m);
    s2 += __shfl_xor(s2, m);
  }
  __shared__ float red[8];
  if ((t & 63) == 0) { red[t >> 6] = s; red[4 + (t >> 6)] = s2; }
  __syncthreads();
  s  = red[0] + red[1] + red[2] + red[3];
  s2 = red[4] + red[5] + red[6] + red[7];
  const float mu = s * (1.0f / 1024.0f);
  const float rs = rsqrtf(s2 * (1.0f / 1024.0f) - mu * mu + 1e-5f);
  const float4 gv = ((const float4*)g)[t];
  const float4 bv = ((const float4*)b)[t];
  u16x4 o;
  o[0] = f2bf((v.x - mu) * rs * gv.x + bv.x);
  o[1] = f2bf((v.y - mu) * rs * gv.y + bv.y);
  o[2] = f2bf((v.z - mu) * rs * gv.z + bv.z);
  o[3] = f2bf((v.w - mu) * rs * gv.w + bv.w);
  *(u16x4*)(out + (size_t)row * 1024 + t * 4) = o;
}

// ---------------------------------------------------------------------------
// Prefix k/v: pk,pv [B,P,C] fp32 -> K/V buffers [B,H,MKV,D] bf16 (rows 0..P)
__global__ __launch_bounds__(256) void prefix_fill(
    const float* __restrict__ pk, const float* __restrict__ pv,
    unsigned short* __restrict__ Kb, unsigned short* __restrict__ Vb) {
  int i = blockIdx.x * 256 + threadIdx.x;  // 65536 total, 8 elems each
  int c8 = i & 127, bp = i >> 7;
  int b = bp >> 6, p = bp & 63;
  int c = c8 << 3, h = c >> 6, d = c & 63;
  size_t sidx = (size_t)bp * 1024 + c;
  size_t didx = (((size_t)(b * 16 + h)) * MKV + p) * 64 + d;
  float4 a = *(const float4*)(pk + sidx);
  float4 a2 = *(const float4*)(pk + sidx + 4);
  u16x8 o;
  o[0] = f2bf(a.x);  o[1] = f2bf(a.y);  o[2] = f2bf(a.z);  o[3] = f2bf(a.w);
  o[4] = f2bf(a2.x); o[5] = f2bf(a2.y); o[6] = f2bf(a2.z); o[7] = f2bf(a2.w);
  *(u16x8*)(Kb + didx) = o;
  a = *(const float4*)(pv + sidx);
  a2 = *(const float4*)(pv + sidx + 4);
  o[0] = f2bf(a.x);  o[1] = f2bf(a.y);  o[2] = f2bf(a.z);  o[3] = f2bf(a.w);
  o[4] = f2bf(a2.x); o[5] = f2bf(a2.y); o[6] = f2bf(a2.z); o[7] = f2bf(a2.w);
  *(u16x8*)(Vb + didx) = o;
}

// ---------------------------------------------------------------------------
// V [BH,MKV,64] -> Vt [BH,64,MKV]  (64x64 tiles through LDS, pad 66 => 4-way max)
__global__ __launch_bounds__(256) void transpose_v(
    const unsigned short* __restrict__ Vb, unsigned short* __restrict__ Vt) {
  __shared__ __align__(16) unsigned short Ts[64 * 66];
  const int kt = blockIdx.x, bh = blockIdx.y;
  const int t = threadIdx.x;
  const unsigned short* src = Vb + ((size_t)bh * MKV + kt * 64) * 64;
#pragma unroll
  for (int rnd = 0; rnd < 2; rnd++) {
    int chunk = rnd * 256 + t;
    int mr = chunk >> 3, d0 = (chunk & 7) << 3;
    u16x8 a = *(const u16x8*)(src + mr * 64 + d0);
#pragma unroll
    for (int j = 0; j < 8; j += 2)
      *(unsigned*)&Ts[mr * 66 + d0 + j] = (unsigned)a[j] | ((unsigned)a[j + 1] << 16);
  }
  __syncthreads();
#pragma unroll
  for (int rnd = 0; rnd < 2; rnd++) {
    int chunk = rnd * 256 + t;
    int dr = chunk >> 3, m0 = (chunk & 7) << 3;
    u16x8 o;
#pragma unroll
    for (int j = 0; j < 8; j++) o[j] = Ts[(m0 + j) * 66 + dr];
    *(u16x8*)(Vt + ((size_t)bh * 64 + dr) * MKV + kt * 64 + m0) = o;
  }
}

// ---------------------------------------------------------------------------
// GEMM: C[M,Nd] = A[M,K] @ Bw[Nd,K]^T, bf16 in, fp32 accum. m97 structure.
template <int EPI>
__global__ __launch_bounds__(256) void gemm_bt(
    const unsigned short* __restrict__ A, const unsigned short* __restrict__ Bw,
    const float* __restrict__ bias, const float* __restrict__ resid,
    float* __restrict__ outf, unsigned short* __restrict__ outb,
    unsigned short* __restrict__ qout, unsigned short* __restrict__ kout,
    unsigned short* __restrict__ vout, int Ndim, int Kdim) {
  __shared__ __align__(16) unsigned short As[4096];
  __shared__ __align__(16) unsigned short Bs[4096];
  const int t = threadIdx.x;
  const int w = t >> 6, l = t & 63;
  const int wr = w >> 1, wc = w & 1;
  const int q4 = l >> 4, r15 = l & 15;
  const int bm = blockIdx.x, bn = blockIdx.y;
  const int srow = t >> 2, scol = (t & 3) << 3;
  const unsigned short* Ap = A + (size_t)(bm * 128 + srow) * Kdim + scol;
  const unsigned short* Bp = Bw + (size_t)(bn * 128 + srow) * Kdim + scol;
  f32x4 acc[4][4] = {};
  const int ard = (wr * 64 + r15) * 32 + q4 * 8;
  const int brd = (wc * 64 + r15) * 32 + q4 * 8;
  for (int kt = 0; kt < Kdim; kt += 32) {
    GLDS16(Ap, &As[t * 8]);
    GLDS16(Ap + (size_t)64 * Kdim, &As[2048 + t * 8]);
    GLDS16(Bp, &Bs[t * 8]);
    GLDS16(Bp + (size_t)64 * Kdim, &Bs[2048 + t * 8]);
    Ap += 32; Bp += 32;
    __syncthreads();
    bf16x8 af[4], bfv[4];
#pragma unroll
    for (int mi = 0; mi < 4; mi++) af[mi] = *(const bf16x8*)&As[ard + mi * 512];
#pragma unroll
    for (int ni = 0; ni < 4; ni++) bfv[ni] = *(const bf16x8*)&Bs[brd + ni * 512];
#pragma unroll
    for (int mi = 0; mi < 4; mi++)
#pragma unroll
      for (int ni = 0; ni < 4; ni++)
        acc[mi][ni] = __builtin_amdgcn_mfma_f32_16x16x32_bf16(
            af[mi], bfv[ni], acc[mi][ni], 0, 0, 0);
    __syncthreads();
  }
  const int orow0 = bm * 128 + wr * 64 + q4 * 4;
  const int ocol0 = bn * 128 + wc * 64 + r15;
  if (EPI == 0) {
    const int which = (bn * 128) >> 10;
#pragma unroll
    for (int mi = 0; mi < 4; mi++)
#pragma unroll
      for (int ni = 0; ni < 4; ni++)
#pragma unroll
        for (int r = 0; r < 4; r++) {
          int m = orow0 + mi * 16 + r;
          int c = ocol0 + ni * 16;
          int cc = c & 1023;
          int h = cc >> 6, d = cc & 63;
          int b = m >> 10, n = m & 1023;
          float v = acc[mi][ni][r];
          if (which == 0)
            qout[(((size_t)(b * 16 + h)) * 1024 + n) * 64 + d] = f2bf(v * 0.125f);
          else if (which == 1)
            kout[(((size_t)(b * 16 + h)) * MKV + 64 + n) * 64 + d] = f2bf(v);
          else
            vout[(((size_t)(b * 16 + h)) * MKV + 64 + n) * 64 + d] = f2bf(v);
        }
  } else if (EPI == 1) {
#pragma unroll
    for (int mi = 0; mi < 4; mi++)
#pragma unroll
      for (int ni = 0; ni < 4; ni++)
#pragma unroll
        for (int r = 0; r < 4; r++) {
          int c = ocol0 + ni * 16;
          size_t idx = (size_t)(orow0 + mi * 16 + r) * Ndim + c;
          outf[idx] = resid[idx] + acc[mi][ni][r] + bias[c];
        }
  } else {
#pragma unroll
    for (int mi = 0; mi < 4; mi++)
#pragma unroll
      for (int ni = 0; ni < 4; ni++)
#pragma unroll
        for (int r = 0; r < 4; r++) {
          int c = ocol0 + ni * 16;
          size_t idx = (size_t)(orow0 + mi * 16 + r) * Ndim + c;
          float z = acc[mi][ni][r] + bias[c];
          outb[idx] = f2bf(z / (1.f + __expf(-1.702f * z)));
        }
  }
}

// ---------------------------------------------------------------------------
// Flash attention v3 — LDS-staged K/V (global_load_lds, double-buffered,
// XOR-swizzled both-sides per rule #21), swapped QK^T, 8 waves x 32 q-rows.
// grid = (bh, qt4): all blocks of a bh land on XCD bh%8 (K/V L2-resident).
__device__ __forceinline__ void online_sm(f32x4 S[4], float& m, float& lsum,
                                          f32x4 Oa[4], unsigned pw[4][2]) {
  float mx = S[0][0];
#pragma unroll
  for (int jc = 0; jc < 4; jc++)
#pragma unroll
    for (int r = 0; r < 4; r++) mx = fmaxf(mx, S[jc][r]);
  mx = fmaxf(mx, __shfl_xor(mx, 16));
  mx = fmaxf(mx, __shfl_xor(mx, 32));
  const float mn = fmaxf(m, mx);
  const float scl = __expf(m - mn);
  m = mn;
  float rs = 0.f;
#pragma unroll
  for (int jc = 0; jc < 4; jc++)
#pragma unroll
    for (int r = 0; r < 4; r++) {
      float p = __expf(S[jc][r] - mn);
      S[jc][r] = p;
      rs += p;
    }
  rs += __shfl_xor(rs, 16);
  rs += __shfl_xor(rs, 32);
  lsum = lsum * scl + rs;
#pragma unroll
  for (int db = 0; db < 4; db++)
#pragma unroll
    for (int r = 0; r < 4; r++) Oa[db][r] *= scl;
#pragma unroll
  for (int jc = 0; jc < 4; jc++) {
    pw[jc][0] = (unsigned)f2bf(S[jc][0]) | ((unsigned)f2bf(S[jc][1]) << 16);
    pw[jc][1] = (unsigned)f2bf(S[jc][2]) | ((unsigned)f2bf(S[jc][3]) << 16);
  }
}

__device__ __forceinline__ bf16x8 pexch(const unsigned pw[4][2], int kk,
                                        int src0, bool lo) {
  const unsigned a0 = pw[2 * kk][0], a1 = pw[2 * kk][1];
  const unsigned b0 = pw[2 * kk + 1][0], b1 = pw[2 * kk + 1][1];
  unsigned wA0 = (unsigned)__shfl((int)a0, src0);
  unsigned wA1 = (unsigned)__shfl((int)a1, src0);
  unsigned wB0 = (unsigned)__shfl((int)b0, src0);
  unsigned wB1 = (unsigned)__shfl((int)b1, src0);
  unsigned wA0h = (unsigned)__shfl((int)a0, src0 + 16);
  unsigned wA1h = (unsigned)__shfl((int)a1, src0 + 16);
  unsigned wB0h = (unsigned)__shfl((int)b0, src0 + 16);
  unsigned wB1h = (unsigned)__shfl((int)b1, src0 + 16);
  union { unsigned u[4]; bf16x8 v; } pf;
  pf.u[0] = lo ? wA0 : wB0;
  pf.u[1] = lo ? wA1 : wB1;
  pf.u[2] = lo ? wA0h : wB0h;
  pf.u[3] = lo ? wA1h : wB1h;
  return pf.v;
}

__global__ __launch_bounds__(512, 4) void flash_attn(
    const unsigned short* __restrict__ Qb, const unsigned short* __restrict__ Kb,
    const unsigned short* __restrict__ Vt, unsigned short* __restrict__ Ob) {
  __shared__ __align__(16) unsigned short KT[2][4096];  // [buf][64 rows][64 cols] swz
  __shared__ __align__(16) unsigned short VT[2][4096];  // [buf][64 d][64 k] swz
  const int t = threadIdx.x;
  const int w = t >> 6, l = t & 63;
  const int g = l >> 4, r15 = l & 15;
  const int bh = blockIdx.x, qt = blockIdx.y;
  const unsigned short* Kbh = Kb + (size_t)bh * MKV * 64;
  const unsigned short* Vbh = Vt + (size_t)bh * 64 * MKV;
  // staging addresses (thread t stages 16B unit t of each 8KB tile)
  const int srow = t >> 3;
  const int scb = ((t & 7) << 4) ^ ((srow & 7) << 4);   // pre-swizzled source col
  const char* Ksrc0 = (const char*)Kbh + srow * 128 + scb;
  const char* Vsrc0 = (const char*)Vbh + srow * (MKV * 2) + scb;
  // Q fragments: 32 q-rows per wave (two 16-groups u=0,1)
  const int qbase = qt * 256 + w * 32;
  const unsigned short* Qr0 = Qb + ((size_t)bh * 1024 + qbase + r15) * 64;
  const bf16x8 qf00 = *(const bf16x8*)(Qr0 + g * 8);
  const bf16x8 qf01 = *(const bf16x8*)(Qr0 + 32 + g * 8);
  const bf16x8 qf10 = *(const bf16x8*)(Qr0 + 16 * 64 + g * 8);
  const bf16x8 qf11 = *(const bf16x8*)(Qr0 + 16 * 64 + 32 + g * 8);
  f32x4 Oa0[4] = {}, Oa1[4] = {};
  float m0 = -1e30f, l0 = 0.f, m1 = -1e30f, l1 = 0.f;
  const int src0 = r15 + ((l & 16) << 1);
  const bool lo = (l < 32);
  const int rx = (r15 & 7) << 4;
  // prologue: stage tile 0 into buf 0
  GLDS16(Ksrc0, &KT[0][t * 8]);
  GLDS16(Vsrc0, &VT[0][t * 8]);
  __syncthreads();
  int cur = 0;
  for (int kt = 0; kt < 17; ++kt) {
    if (kt < 16) {  // stage next tile into the other buffer (overlaps compute)
      GLDS16(Ksrc0 + (kt + 1) * 8192, &KT[cur ^ 1][t * 8]);
      GLDS16(Vsrc0 + (kt + 1) * 128, &VT[cur ^ 1][t * 8]);
    }
    const char* Kl = (const char*)&KT[cur][0];
    const char* Vl = (const char*)&VT[cur][0];
    // ---- QK^T (S^T = K · Q^T), K-frags from swizzled LDS
    f32x4 S0[4], S1[4];
#pragma unroll
    for (int jc = 0; jc < 4; jc++) {
      const char* kr = Kl + jc * 2048 + r15 * 128;
      bf16x8 k0 = *(const bf16x8*)(kr + ((g * 16) ^ rx));
      bf16x8 k1 = *(const bf16x8*)(kr + ((64 + g * 16) ^ rx));
      f32x4 a0 = {}, a1 = {};
      a0 = __builtin_amdgcn_mfma_f32_16x16x32_bf16(k0, qf00, a0, 0, 0, 0);
      a0 = __builtin_amdgcn_mfma_f32_16x16x32_bf16(k1, qf01, a0, 0, 0, 0);
      a1 = __builtin_amdgcn_mfma_f32_16x16x32_bf16(k0, qf10, a1, 0, 0, 0);
      a1 = __builtin_amdgcn_mfma_f32_16x16x32_bf16(k1, qf11, a1, 0, 0, 0);
      S0[jc] = a0; S1[jc] = a1;
    }
    // ---- online softmax (lane owns q=r15 of its group)
    unsigned pw0[4][2], pw1[4][2];
    online_sm(S0, m0, l0, Oa0, pw0);
    online_sm(S1, m1, l1, Oa1, pw1);
    // ---- PV: O^T += V^T · P, V-frags from swizzled LDS, P via lane exchange
#pragma unroll
    for (int kk = 0; kk < 2; kk++) {
      bf16x8 pf0 = pexch(pw0, kk, src0, lo);
      bf16x8 pf1 = pexch(pw1, kk, src0, lo);
#pragma unroll
      for (int db = 0; db < 4; db++) {
        bf16x8 va = *(const bf16x8*)(Vl + db * 2048 + r15 * 128 +
                                     ((kk * 64 + g * 16) ^ rx));
        Oa0[db] = __builtin_amdgcn_mfma_f32_16x16x32_bf16(va, pf0, Oa0[db], 0, 0, 0);
        Oa1[db] = __builtin_amdgcn_mfma_f32_16x16x32_bf16(va, pf1, Oa1[db], 0, 0, 0);
      }
    }
    __syncthreads();   // drains vmcnt(0): next buf staged; buf[cur] reads done
    cur ^= 1;
  }
  const int b = bh >> 4, h = bh & 15;
  const float i0 = 1.f / l0, i1 = 1.f / l1;
  const int n0 = qbase + r15;
#pragma unroll
  for (int db = 0; db < 4; db++) {
    u16x4 o;
#pragma unroll
    for (int r = 0; r < 4; r++) o[r] = f2bf(Oa0[db][r] * i0);
    *(u16x4*)(Ob + ((size_t)b * 1024 + n0) * 1024 + h * 64 + db * 16 + g * 4) = o;
#pragma unroll
    for (int r = 0; r < 4; r++) o[r] = f2bf(Oa1[db][r] * i1);
    *(u16x4*)(Ob + ((size_t)b * 1024 + n0 + 16) * 1024 + h * 64 + db * 16 + g * 4) = o;
  }
}

// ---------------------------------------------------------------------------
extern "C" void kernel_launch(void* const* d_in, const int* in_sizes, int n_in,
                              void* d_out, int out_size, void* d_ws, size_t ws_size,
                              hipStream_t stream) {
  const float* x       = (const float*)d_in[0];
  const float* pk      = (const float*)d_in[1];
  const float* pv      = (const float*)d_in[2];
  const float* qkv_w   = (const float*)d_in[3];
  const float* proj_w  = (const float*)d_in[4];
  const float* proj_b  = (const float*)d_in[5];
  const float* ln1_g   = (const float*)d_in[6];
  const float* ln1_b   = (const float*)d_in[7];
  const float* ln2_g   = (const float*)d_in[8];
  const float* ln2_b   = (const float*)d_in[9];
  const float* fc_w    = (const float*)d_in[10];
  const float* fc_b    = (const float*)d_in[11];
  const float* cproj_w = (const float*)d_in[12];
  const float* cproj_b = (const float*)d_in[13];
  float* out = (float*)d_out;
  char* ws = (char*)d_ws;

  unsigned short* qkv_wb   = (unsigned short*)(ws + 0);          // 6291456
  unsigned short* proj_wb  = (unsigned short*)(ws + 6291456);    // 2097152
  unsigned short* fc_wb    = (unsigned short*)(ws + 8388608);    // 8388608
  unsigned short* cproj_wb = (unsigned short*)(ws + 16777216);   // 8388608
  float*          x1       = (float*)(ws + 25165824);            // 33554432
  unsigned short* h1       = (unsigned short*)(ws + 58720256);   // 16777216
  unsigned short* o_b      = h1;                                 // alias (h1 dead)
  unsigned short* h2       = (unsigned short*)(ws + 75497472);   // 16777216
  unsigned short* q_buf    = (unsigned short*)(ws + 92274688);   // 16777216
  unsigned short* Kb       = (unsigned short*)(ws + 109051904);  // 17825792
  unsigned short* Vb       = (unsigned short*)(ws + 126877696);  // 17825792
  unsigned short* Vt       = (unsigned short*)(ws + 144703488);  // 17825792
  unsigned short* h3       = (unsigned short*)(ws + 92274688);   // alias (dead)
  if (ws_size < 162529280u) return;

  cast_bf16_k<<<1536, 256, 0, stream>>>(qkv_w, qkv_wb, 393216);
  cast_bf16_k<<<512, 256, 0, stream>>>(proj_w, proj_wb, 131072);
  cast_bf16_k<<<2048, 256, 0, stream>>>(fc_w, fc_wb, 524288);
  cast_bf16_k<<<2048, 256, 0, stream>>>(cproj_w, cproj_wb, 524288);
  ln_bf16<<<ROWS, 256, 0, stream>>>(x, ln1_g, ln1_b, h1);
  prefix_fill<<<256, 256, 0, stream>>>(pk, pv, Kb, Vb);
  gemm_bt<0><<<dim3(64, 24), 256, 0, stream>>>(h1, qkv_wb, nullptr, nullptr, nullptr,
                                               nullptr, q_buf, Kb, Vb, 3072, 1024);
  transpose_v<<<dim3(17, 128), 256, 0, stream>>>(Vb, Vt);
  flash_attn<<<dim3(128, 4), 512, 0, stream>>>(q_buf, Kb, Vt, o_b);
  gemm_bt<1><<<dim3(64, 8), 256, 0, stream>>>(o_b, proj_wb, proj_b, x, x1, nullptr,
                                              nullptr, nullptr, nullptr, 1024, 1024);
  ln_bf16<<<ROWS, 256, 0, stream>>>(x1, ln2_g, ln2_b, h2);
  gemm_bt<2><<<dim3(64, 32), 256, 0, stream>>>(h2, fc_wb, fc_b, nullptr, nullptr, h3,
                                               nullptr, nullptr, nullptr, 4096, 1024);
  gemm_bt<1><<<dim3(64, 8), 256, 0, stream>>>(h3, cproj_wb, cproj_b, x1, out, nullptr,
                                              nullptr, nullptr, nullptr, 1024, 4096);
}

// Round 4
// 360.872 us; speedup vs baseline: 1.7096x; 1.2265x over previous
//
#include <hip/hip_runtime.h>

// Problem constants
#define B_   8
#define N_   1024
#define C_   1024
#define H_   16
#define P_   64
#define D_   64
#define MKV  1088      // P_ + N_
#define ROWS 8192      // B_*N_

typedef float f32x4 __attribute__((ext_vector_type(4)));
typedef __bf16 bf16x8 __attribute__((ext_vector_type(8)));
typedef unsigned short u16x8 __attribute__((ext_vector_type(8)));
typedef unsigned short u16x4 __attribute__((ext_vector_type(4)));

__device__ __forceinline__ unsigned short f2bf(float f) {
  unsigned u = __float_as_uint(f);
  u += 0x7fffu + ((u >> 16) & 1u);   // round-to-nearest-even
  return (unsigned short)(u >> 16);
}

#define GLDS16(g, l)                                                          \
  __builtin_amdgcn_global_load_lds(                                           \
      (const __attribute__((address_space(1))) void*)(g),                     \
      (__attribute__((address_space(3))) void*)(l), 16, 0, 0)

// ---------------------------------------------------------------------------
// fp32 -> bf16 cast (weights), 8 elems/thread
__global__ __launch_bounds__(256) void cast_bf16_k(
    const float* __restrict__ in, unsigned short* __restrict__ out, int n8) {
  int i = blockIdx.x * 256 + threadIdx.x;
  if (i >= n8) return;
  const float4 a = ((const float4*)in)[i * 2];
  const float4 c = ((const float4*)in)[i * 2 + 1];
  u16x8 o;
  o[0] = f2bf(a.x); o[1] = f2bf(a.y); o[2] = f2bf(a.z); o[3] = f2bf(a.w);
  o[4] = f2bf(c.x); o[5] = f2bf(c.y); o[6] = f2bf(c.z); o[7] = f2bf(c.w);
  *(u16x8*)(out + (size_t)i * 8) = o;
}

// ---------------------------------------------------------------------------
// LayerNorm (fp32 in) -> bf16 out.  One block per row of 1024.
__global__ __launch_bounds__(256) void ln_bf16(
    const float* __restrict__ x, const float* __restrict__ g,
    const float* __restrict__ b, unsigned short* __restrict__ out) {
  const int row = blockIdx.x, t = threadIdx.x;
  const float4 v = ((const float4*)(x + (size_t)row * 1024))[t];
  float s  = v.x + v.y + v.z + v.w;
  float s2 = v.x * v.x + v.y * v.y + v.z * v.z + v.w * v.w;
#pragma unroll
  for (int m = 1; m < 64; m <<= 1) {
    s  += __shfl_xor(s, m);
    s2 += __shfl_xor(s2, m);
  }
  __shared__ float red[8];
  if ((t & 63) == 0) { red[t >> 6] = s; red[4 + (t >> 6)] = s2; }
  __syncthreads();
  s  = red[0] + red[1] + red[2] + red[3];
  s2 = red[4] + red[5] + red[6] + red[7];
  const float mu = s * (1.0f / 1024.0f);
  const float rs = rsqrtf(s2 * (1.0f / 1024.0f) - mu * mu + 1e-5f);
  const float4 gv = ((const float4*)g)[t];
  const float4 bv = ((const float4*)b)[t];
  u16x4 o;
  o[0] = f2bf((v.x - mu) * rs * gv.x + bv.x);
  o[1] = f2bf((v.y - mu) * rs * gv.y + bv.y);
  o[2] = f2bf((v.z - mu) * rs * gv.z + bv.z);
  o[3] = f2bf((v.w - mu) * rs * gv.w + bv.w);
  *(u16x4*)(out + (size_t)row * 1024 + t * 4) = o;
}

// ---------------------------------------------------------------------------
// Prefix k/v: pk,pv [B,P,C] fp32 -> K/V buffers [B,H,MKV,D] bf16 (rows 0..P)
__global__ __launch_bounds__(256) void prefix_fill(
    const float* __restrict__ pk, const float* __restrict__ pv,
    unsigned short* __restrict__ Kb, unsigned short* __restrict__ Vb) {
  int i = blockIdx.x * 256 + threadIdx.x;  // 65536 total, 8 elems each
  int c8 = i & 127, bp = i >> 7;
  int b = bp >> 6, p = bp & 63;
  int c = c8 << 3, h = c >> 6, d = c & 63;
  size_t sidx = (size_t)bp * 1024 + c;
  size_t didx = (((size_t)(b * 16 + h)) * MKV + p) * 64 + d;
  float4 a = *(const float4*)(pk + sidx);
  float4 a2 = *(const float4*)(pk + sidx + 4);
  u16x8 o;
  o[0] = f2bf(a.x);  o[1] = f2bf(a.y);  o[2] = f2bf(a.z);  o[3] = f2bf(a.w);
  o[4] = f2bf(a2.x); o[5] = f2bf(a2.y); o[6] = f2bf(a2.z); o[7] = f2bf(a2.w);
  *(u16x8*)(Kb + didx) = o;
  a = *(const float4*)(pv + sidx);
  a2 = *(const float4*)(pv + sidx + 4);
  o[0] = f2bf(a.x);  o[1] = f2bf(a.y);  o[2] = f2bf(a.z);  o[3] = f2bf(a.w);
  o[4] = f2bf(a2.x); o[5] = f2bf(a2.y); o[6] = f2bf(a2.z); o[7] = f2bf(a2.w);
  *(u16x8*)(Vb + didx) = o;
}

// ---------------------------------------------------------------------------
// V [BH,MKV,64] -> Vt [BH,64,MKV]  (64x64 tiles through LDS, pad 66 => 4-way max)
__global__ __launch_bounds__(256) void transpose_v(
    const unsigned short* __restrict__ Vb, unsigned short* __restrict__ Vt) {
  __shared__ __align__(16) unsigned short Ts[64 * 66];
  const int kt = blockIdx.x, bh = blockIdx.y;
  const int t = threadIdx.x;
  const unsigned short* src = Vb + ((size_t)bh * MKV + kt * 64) * 64;
#pragma unroll
  for (int rnd = 0; rnd < 2; rnd++) {
    int chunk = rnd * 256 + t;
    int mr = chunk >> 3, d0 = (chunk & 7) << 3;
    u16x8 a = *(const u16x8*)(src + mr * 64 + d0);
#pragma unroll
    for (int j = 0; j < 8; j += 2)
      *(unsigned*)&Ts[mr * 66 + d0 + j] = (unsigned)a[j] | ((unsigned)a[j + 1] << 16);
  }
  __syncthreads();
#pragma unroll
  for (int rnd = 0; rnd < 2; rnd++) {
    int chunk = rnd * 256 + t;
    int dr = chunk >> 3, m0 = (chunk & 7) << 3;
    u16x8 o;
#pragma unroll
    for (int j = 0; j < 8; j++) o[j] = Ts[(m0 + j) * 66 + dr];
    *(u16x8*)(Vt + ((size_t)bh * 64 + dr) * MKV + kt * 64 + m0) = o;
  }
}

// ---------------------------------------------------------------------------
// GEMM v2: C[M,Nd] = A[M,K] @ Bw[Nd,K]^T, bf16 in, fp32 accum.
// BM=128, BN=256, BK=64, 512 threads (8 waves as 2x4, 64x64 out each).
// 3-stage LDS pipeline (144 KiB dynamic), counted vmcnt(6) (T4), one barrier
// per K-tile (T3-minimum), XOR-swizzled LDS both-sides (T2, rule #21).
// EPI 0: qkv scatter; EPI 1: resid+acc+bias fp32; EPI 2: quickgelu bf16.
#define GEMM_LDS 147456
template <int EPI>
__global__ __launch_bounds__(512, 2) void gemm3s(
    const unsigned short* __restrict__ A, const unsigned short* __restrict__ Bw,
    const float* __restrict__ bias, const float* __restrict__ resid,
    float* __restrict__ outf, unsigned short* __restrict__ outb,
    unsigned short* __restrict__ qout, unsigned short* __restrict__ kout,
    unsigned short* __restrict__ vout, int Ndim, int Kdim) {
  extern __shared__ __align__(16) char smem[];  // A: 3x16KB @0, B: 3x32KB @49152
  const int t = threadIdx.x;
  const int w = t >> 6, l = t & 63;
  const int wr = w >> 2, wc = w & 3;           // wave grid 2(M) x 4(N)
  const int q4 = l >> 4, r15 = l & 15;
  const int bm = blockIdx.x, bn = blockIdx.y;
  const int NS = Kdim >> 6;                    // K-tiles of 64
  // ---- staging addresses (thread t loads A x2 + B x4 16B granules/tile)
  const int srow = t >> 3;                     // 0..63
  const int scolb = (t & 7) << 4;
  const int sswz = scolb ^ ((srow & 7) << 4);  // pre-swizzled source col (bytes)
  const size_t krb = (size_t)Kdim * 2;         // row stride bytes
  const char* Asrc0 = (const char*)(A + (size_t)(bm * 128 + srow) * Kdim) + sswz;
  const char* Asrc1 = Asrc0 + 64 * krb;
  const char* Bsrc0 = (const char*)(Bw + (size_t)(bn * 256 + srow) * Kdim) + sswz;
  const char* Bsrc1 = Bsrc0 + 64 * krb;
  const char* Bsrc2 = Bsrc0 + 128 * krb;
  const char* Bsrc3 = Bsrc0 + 192 * krb;
  char* Ad0 = smem + t * 16;
  char* Bd0 = smem + 49152 + t * 16;
#define STAGE_TILE(s_, st_)                                                   \
  {                                                                           \
    const int koff = (s_) << 7;                                               \
    char* Ad = Ad0 + (st_) * 16384;                                           \
    char* Bd = Bd0 + (st_) * 32768;                                           \
    GLDS16(Asrc0 + koff, Ad);                                                 \
    GLDS16(Asrc1 + koff, Ad + 8192);                                          \
    GLDS16(Bsrc0 + koff, Bd);                                                 \
    GLDS16(Bsrc1 + koff, Bd + 8192);                                          \
    GLDS16(Bsrc2 + koff, Bd + 16384);                                         \
    GLDS16(Bsrc3 + koff, Bd + 24576);                                         \
  }
  // ---- fragment read offsets (swizzled)
  const int rx = (r15 & 7) << 4;
  const int c0 = (q4 * 16) ^ rx;               // kk=0 col byte
  const int arow = (wr * 64 + r15) * 128;
  const int brow = (wc * 64 + r15) * 128;
  f32x4 acc[4][4] = {};
  // ---- prologue: stage tiles 0,1
  STAGE_TILE(0, 0);
  STAGE_TILE(1, 1);
  int st = 0;
  for (int s = 0; s < NS; ++s) {
    __builtin_amdgcn_sched_barrier(0);
    asm volatile("s_waitcnt lgkmcnt(0)" ::: "memory");
    if (s == NS - 1) {
      asm volatile("s_waitcnt vmcnt(0)" ::: "memory");
    } else {
      asm volatile("s_waitcnt vmcnt(6)" ::: "memory");
    }
    __builtin_amdgcn_s_barrier();
    __builtin_amdgcn_sched_barrier(0);
    if (s + 2 < NS) {
      int st2 = st + 2; if (st2 >= 3) st2 -= 3;
      STAGE_TILE(s + 2, st2);
    }
    const char* Ab = smem + st * 16384 + arow;
    const char* Bb = smem + 49152 + st * 32768 + brow;
    bf16x8 af[4][2], bfv[4][2];
#pragma unroll
    for (int mi = 0; mi < 4; mi++) {
      af[mi][0] = *(const bf16x8*)(Ab + mi * 2048 + c0);
      af[mi][1] = *(const bf16x8*)(Ab + mi * 2048 + (c0 ^ 64));
    }
#pragma unroll
    for (int ni = 0; ni < 4; ni++) {
      bfv[ni][0] = *(const bf16x8*)(Bb + ni * 2048 + c0);
      bfv[ni][1] = *(const bf16x8*)(Bb + ni * 2048 + (c0 ^ 64));
    }
#pragma unroll
    for (int kk = 0; kk < 2; kk++)
#pragma unroll
      for (int mi = 0; mi < 4; mi++)
#pragma unroll
        for (int ni = 0; ni < 4; ni++)
          acc[mi][ni] = __builtin_amdgcn_mfma_f32_16x16x32_bf16(
              af[mi][kk], bfv[ni][kk], acc[mi][ni], 0, 0, 0);
    st++; if (st == 3) st = 0;
  }
  // ---- epilogue.  D layout: row=(l>>4)*4+reg, col=l&15 (m89/m91 verified).
  const int orow0 = bm * 128 + wr * 64 + q4 * 4;
  const int ocol0 = bn * 256 + wc * 64 + r15;
  if (EPI == 0) {
    const int which = (bn * 256) >> 10;  // uniform per block (256 | 1024)
#pragma unroll
    for (int mi = 0; mi < 4; mi++)
#pragma unroll
      for (int ni = 0; ni < 4; ni++)
#pragma unroll
        for (int r = 0; r < 4; r++) {
          int m = orow0 + mi * 16 + r;
          int c = ocol0 + ni * 16;
          int cc = c & 1023;
          int h = cc >> 6, d = cc & 63;
          int b = m >> 10, n = m & 1023;
          float v = acc[mi][ni][r];
          if (which == 0)
            qout[(((size_t)(b * 16 + h)) * 1024 + n) * 64 + d] = f2bf(v * 0.125f);
          else if (which == 1)
            kout[(((size_t)(b * 16 + h)) * MKV + 64 + n) * 64 + d] = f2bf(v);
          else
            vout[(((size_t)(b * 16 + h)) * MKV + 64 + n) * 64 + d] = f2bf(v);
        }
  } else if (EPI == 1) {
#pragma unroll
    for (int mi = 0; mi < 4; mi++)
#pragma unroll
      for (int ni = 0; ni < 4; ni++)
#pragma unroll
        for (int r = 0; r < 4; r++) {
          int c = ocol0 + ni * 16;
          size_t idx = (size_t)(orow0 + mi * 16 + r) * Ndim + c;
          outf[idx] = resid[idx] + acc[mi][ni][r] + bias[c];
        }
  } else {
#pragma unroll
    for (int mi = 0; mi < 4; mi++)
#pragma unroll
      for (int ni = 0; ni < 4; ni++)
#pragma unroll
        for (int r = 0; r < 4; r++) {
          int c = ocol0 + ni * 16;
          size_t idx = (size_t)(orow0 + mi * 16 + r) * Ndim + c;
          float z = acc[mi][ni][r] + bias[c];
          outb[idx] = f2bf(z / (1.f + __expf(-1.702f * z)));
        }
  }
#undef STAGE_TILE
}

// ---------------------------------------------------------------------------
// Flash attention v3 — LDS-staged K/V (global_load_lds, double-buffered,
// XOR-swizzled both-sides per rule #21), swapped QK^T, 8 waves x 32 q-rows.
// grid = (bh, qt4): all blocks of a bh land on XCD bh%8 (K/V L2-resident).
__device__ __forceinline__ void online_sm(f32x4 S[4], float& m, float& lsum,
                                          f32x4 Oa[4], unsigned pw[4][2]) {
  float mx = S[0][0];
#pragma unroll
  for (int jc = 0; jc < 4; jc++)
#pragma unroll
    for (int r = 0; r < 4; r++) mx = fmaxf(mx, S[jc][r]);
  mx = fmaxf(mx, __shfl_xor(mx, 16));
  mx = fmaxf(mx, __shfl_xor(mx, 32));
  const float mn = fmaxf(m, mx);
  const float scl = __expf(m - mn);
  m = mn;
  float rs = 0.f;
#pragma unroll
  for (int jc = 0; jc < 4; jc++)
#pragma unroll
    for (int r = 0; r < 4; r++) {
      float p = __expf(S[jc][r] - mn);
      S[jc][r] = p;
      rs += p;
    }
  rs += __shfl_xor(rs, 16);
  rs += __shfl_xor(rs, 32);
  lsum = lsum * scl + rs;
#pragma unroll
  for (int db = 0; db < 4; db++)
#pragma unroll
    for (int r = 0; r < 4; r++) Oa[db][r] *= scl;
#pragma unroll
  for (int jc = 0; jc < 4; jc++) {
    pw[jc][0] = (unsigned)f2bf(S[jc][0]) | ((unsigned)f2bf(S[jc][1]) << 16);
    pw[jc][1] = (unsigned)f2bf(S[jc][2]) | ((unsigned)f2bf(S[jc][3]) << 16);
  }
}

__device__ __forceinline__ bf16x8 pexch(const unsigned pw[4][2], int kk,
                                        int src0, bool lo) {
  const unsigned a0 = pw[2 * kk][0], a1 = pw[2 * kk][1];
  const unsigned b0 = pw[2 * kk + 1][0], b1 = pw[2 * kk + 1][1];
  unsigned wA0 = (unsigned)__shfl((int)a0, src0);
  unsigned wA1 = (unsigned)__shfl((int)a1, src0);
  unsigned wB0 = (unsigned)__shfl((int)b0, src0);
  unsigned wB1 = (unsigned)__shfl((int)b1, src0);
  unsigned wA0h = (unsigned)__shfl((int)a0, src0 + 16);
  unsigned wA1h = (unsigned)__shfl((int)a1, src0 + 16);
  unsigned wB0h = (unsigned)__shfl((int)b0, src0 + 16);
  unsigned wB1h = (unsigned)__shfl((int)b1, src0 + 16);
  union { unsigned u[4]; bf16x8 v; } pf;
  pf.u[0] = lo ? wA0 : wB0;
  pf.u[1] = lo ? wA1 : wB1;
  pf.u[2] = lo ? wA0h : wB0h;
  pf.u[3] = lo ? wA1h : wB1h;
  return pf.v;
}

__global__ __launch_bounds__(512, 4) void flash_attn(
    const unsigned short* __restrict__ Qb, const unsigned short* __restrict__ Kb,
    const unsigned short* __restrict__ Vt, unsigned short* __restrict__ Ob) {
  __shared__ __align__(16) unsigned short KT[2][4096];  // [buf][64 rows][64 cols] swz
  __shared__ __align__(16) unsigned short VT[2][4096];  // [buf][64 d][64 k] swz
  const int t = threadIdx.x;
  const int w = t >> 6, l = t & 63;
  const int g = l >> 4, r15 = l & 15;
  const int bh = blockIdx.x, qt = blockIdx.y;
  const unsigned short* Kbh = Kb + (size_t)bh * MKV * 64;
  const unsigned short* Vbh = Vt + (size_t)bh * 64 * MKV;
  const int srow = t >> 3;
  const int scb = ((t & 7) << 4) ^ ((srow & 7) << 4);   // pre-swizzled source col
  const char* Ksrc0 = (const char*)Kbh + srow * 128 + scb;
  const char* Vsrc0 = (const char*)Vbh + srow * (MKV * 2) + scb;
  const int qbase = qt * 256 + w * 32;
  const unsigned short* Qr0 = Qb + ((size_t)bh * 1024 + qbase + r15) * 64;
  const bf16x8 qf00 = *(const bf16x8*)(Qr0 + g * 8);
  const bf16x8 qf01 = *(const bf16x8*)(Qr0 + 32 + g * 8);
  const bf16x8 qf10 = *(const bf16x8*)(Qr0 + 16 * 64 + g * 8);
  const bf16x8 qf11 = *(const bf16x8*)(Qr0 + 16 * 64 + 32 + g * 8);
  f32x4 Oa0[4] = {}, Oa1[4] = {};
  float m0 = -1e30f, l0 = 0.f, m1 = -1e30f, l1 = 0.f;
  const int src0 = r15 + ((l & 16) << 1);
  const bool lo = (l < 32);
  const int rx = (r15 & 7) << 4;
  GLDS16(Ksrc0, &KT[0][t * 8]);
  GLDS16(Vsrc0, &VT[0][t * 8]);
  __syncthreads();
  int cur = 0;
  for (int kt = 0; kt < 17; ++kt) {
    if (kt < 16) {
      GLDS16(Ksrc0 + (kt + 1) * 8192, &KT[cur ^ 1][t * 8]);
      GLDS16(Vsrc0 + (kt + 1) * 128, &VT[cur ^ 1][t * 8]);
    }
    const char* Kl = (const char*)&KT[cur][0];
    const char* Vl = (const char*)&VT[cur][0];
    f32x4 S0[4], S1[4];
#pragma unroll
    for (int jc = 0; jc < 4; jc++) {
      const char* kr = Kl + jc * 2048 + r15 * 128;
      bf16x8 k0 = *(const bf16x8*)(kr + ((g * 16) ^ rx));
      bf16x8 k1 = *(const bf16x8*)(kr + ((64 + g * 16) ^ rx));
      f32x4 a0 = {}, a1 = {};
      a0 = __builtin_amdgcn_mfma_f32_16x16x32_bf16(k0, qf00, a0, 0, 0, 0);
      a0 = __builtin_amdgcn_mfma_f32_16x16x32_bf16(k1, qf01, a0, 0, 0, 0);
      a1 = __builtin_amdgcn_mfma_f32_16x16x32_bf16(k0, qf10, a1, 0, 0, 0);
      a1 = __builtin_amdgcn_mfma_f32_16x16x32_bf16(k1, qf11, a1, 0, 0, 0);
      S0[jc] = a0; S1[jc] = a1;
    }
    unsigned pw0[4][2], pw1[4][2];
    online_sm(S0, m0, l0, Oa0, pw0);
    online_sm(S1, m1, l1, Oa1, pw1);
#pragma unroll
    for (int kk = 0; kk < 2; kk++) {
      bf16x8 pf0 = pexch(pw0, kk, src0, lo);
      bf16x8 pf1 = pexch(pw1, kk, src0, lo);
#pragma unroll
      for (int db = 0; db < 4; db++) {
        bf16x8 va = *(const bf16x8*)(Vl + db * 2048 + r15 * 128 +
                                     ((kk * 64 + g * 16) ^ rx));
        Oa0[db] = __builtin_amdgcn_mfma_f32_16x16x32_bf16(va, pf0, Oa0[db], 0, 0, 0);
        Oa1[db] = __builtin_amdgcn_mfma_f32_16x16x32_bf16(va, pf1, Oa1[db], 0, 0, 0);
      }
    }
    __syncthreads();
    cur ^= 1;
  }
  const int b = bh >> 4, h = bh & 15;
  const float i0 = 1.f / l0, i1 = 1.f / l1;
  const int n0 = qbase + r15;
#pragma unroll
  for (int db = 0; db < 4; db++) {
    u16x4 o;
#pragma unroll
    for (int r = 0; r < 4; r++) o[r] = f2bf(Oa0[db][r] * i0);
    *(u16x4*)(Ob + ((size_t)b * 1024 + n0) * 1024 + h * 64 + db * 16 + g * 4) = o;
#pragma unroll
    for (int r = 0; r < 4; r++) o[r] = f2bf(Oa1[db][r] * i1);
    *(u16x4*)(Ob + ((size_t)b * 1024 + n0 + 16) * 1024 + h * 64 + db * 16 + g * 4) = o;
  }
}

// ---------------------------------------------------------------------------
extern "C" void kernel_launch(void* const* d_in, const int* in_sizes, int n_in,
                              void* d_out, int out_size, void* d_ws, size_t ws_size,
                              hipStream_t stream) {
  const float* x       = (const float*)d_in[0];
  const float* pk      = (const float*)d_in[1];
  const float* pv      = (const float*)d_in[2];
  const float* qkv_w   = (const float*)d_in[3];
  const float* proj_w  = (const float*)d_in[4];
  const float* proj_b  = (const float*)d_in[5];
  const float* ln1_g   = (const float*)d_in[6];
  const float* ln1_b   = (const float*)d_in[7];
  const float* ln2_g   = (const float*)d_in[8];
  const float* ln2_b   = (const float*)d_in[9];
  const float* fc_w    = (const float*)d_in[10];
  const float* fc_b    = (const float*)d_in[11];
  const float* cproj_w = (const float*)d_in[12];
  const float* cproj_b = (const float*)d_in[13];
  float* out = (float*)d_out;
  char* ws = (char*)d_ws;

  unsigned short* qkv_wb   = (unsigned short*)(ws + 0);          // 6291456
  unsigned short* proj_wb  = (unsigned short*)(ws + 6291456);    // 2097152
  unsigned short* fc_wb    = (unsigned short*)(ws + 8388608);    // 8388608
  unsigned short* cproj_wb = (unsigned short*)(ws + 16777216);   // 8388608
  float*          x1       = (float*)(ws + 25165824);            // 33554432
  unsigned short* h1       = (unsigned short*)(ws + 58720256);   // 16777216
  unsigned short* o_b      = h1;                                 // alias (h1 dead)
  unsigned short* h2       = (unsigned short*)(ws + 75497472);   // 16777216
  unsigned short* q_buf    = (unsigned short*)(ws + 92274688);   // 16777216
  unsigned short* Kb       = (unsigned short*)(ws + 109051904);  // 17825792
  unsigned short* Vb       = (unsigned short*)(ws + 126877696);  // 17825792
  unsigned short* Vt       = (unsigned short*)(ws + 144703488);  // 17825792
  unsigned short* h3       = (unsigned short*)(ws + 92274688);   // alias (dead)
  if (ws_size < 162529280u) return;

  // allow 144KB dynamic LDS (idempotent, host-side only — capture-safe)
  (void)hipFuncSetAttribute((const void*)gemm3s<0>,
      hipFuncAttributeMaxDynamicSharedMemorySize, GEMM_LDS);
  (void)hipFuncSetAttribute((const void*)gemm3s<1>,
      hipFuncAttributeMaxDynamicSharedMemorySize, GEMM_LDS);
  (void)hipFuncSetAttribute((const void*)gemm3s<2>,
      hipFuncAttributeMaxDynamicSharedMemorySize, GEMM_LDS);

  cast_bf16_k<<<1536, 256, 0, stream>>>(qkv_w, qkv_wb, 393216);
  cast_bf16_k<<<512, 256, 0, stream>>>(proj_w, proj_wb, 131072);
  cast_bf16_k<<<2048, 256, 0, stream>>>(fc_w, fc_wb, 524288);
  cast_bf16_k<<<2048, 256, 0, stream>>>(cproj_w, cproj_wb, 524288);
  ln_bf16<<<ROWS, 256, 0, stream>>>(x, ln1_g, ln1_b, h1);
  prefix_fill<<<256, 256, 0, stream>>>(pk, pv, Kb, Vb);
  gemm3s<0><<<dim3(64, 12), 512, GEMM_LDS, stream>>>(
      h1, qkv_wb, nullptr, nullptr, nullptr, nullptr, q_buf, Kb, Vb, 3072, 1024);
  transpose_v<<<dim3(17, 128), 256, 0, stream>>>(Vb, Vt);
  flash_attn<<<dim3(128, 4), 512, 0, stream>>>(q_buf, Kb, Vt, o_b);
  gemm3s<1><<<dim3(64, 4), 512, GEMM_LDS, stream>>>(
      o_b, proj_wb, proj_b, x, x1, nullptr, nullptr, nullptr, nullptr, 1024, 1024);
  ln_bf16<<<ROWS, 256, 0, stream>>>(x1, ln2_g, ln2_b, h2);
  gemm3s<2><<<dim3(64, 16), 512, GEMM_LDS, stream>>>(
      h2, fc_wb, fc_b, nullptr, nullptr, h3, nullptr, nullptr, nullptr, 4096, 1024);
  gemm3s<1><<<dim3(64, 4), 512, GEMM_LDS, stream>>>(
      h3, cproj_wb, cproj_b, x1, out, nullptr, nullptr, nullptr, nullptr, 1024, 4096);
}